// Round 5
// baseline (2107.990 us; speedup 1.0000x reference)
//
#include <hip/hip_runtime.h>
#include <hip/hip_fp16.h>
#include <cstdint>
#include <cstddef>

typedef _Float16 f16;
typedef _Float16 f16x2 __attribute__((ext_vector_type(2)));
typedef _Float16 f16x4 __attribute__((ext_vector_type(4)));
typedef _Float16 f16x8 __attribute__((ext_vector_type(8)));
typedef int i32x4 __attribute__((ext_vector_type(4)));

#define S_LEN 2048
#define BATCH 64
#define I_DIM 128
#define H_DIM 512
#define O_DIM 64

// v_dot2_f32_f16 (fp32 accumulate — used in the small GEMMs only).
__device__ __forceinline__ float fdot2f(f16x2 a, f16x2 b, float c) {
#if __has_builtin(__builtin_amdgcn_fdot2)
    return __builtin_amdgcn_fdot2(a, b, c, false);
#else
    return c + (float)a.x * (float)b.x + (float)a.y * (float)b.y;
#endif
}

// v_dot4_i32_i8: 4-way i8 MAC, i32 accumulate.
__device__ __forceinline__ int sdot4(int a, int b, int c) {
#if __has_builtin(__builtin_amdgcn_sdot4)
    return __builtin_amdgcn_sdot4(a, b, c, false);
#else
    int r = c;
#pragma unroll
    for (int i = 0; i < 4; ++i) {
        int av = (a << (24 - 8 * i)) >> 24;
        int bv = (b << (24 - 8 * i)) >> 24;
        r += av * bv;
    }
    return r;
#endif
}

// DPP quad_perm cross-lane (xor1: 0xB1, xor2: 0x4E) — VALU, no LDS.
template <int CTRL>
__device__ __forceinline__ int dpp_qi(int v) {
    return __builtin_amdgcn_update_dpp(0, v, CTRL, 0xF, 0xF, true);
}

// ---------------------------------------------------------------------------
// Phase 1: u[row][c] = sum_k x[row][k] * Wih[k][c], rows = B*S, K=128, N=512.
// (unchanged)
// ---------------------------------------------------------------------------
__global__ __launch_bounds__(256)
void u_gemm_kernel(const float* __restrict__ x, const float* __restrict__ Wih,
                   f16* __restrict__ u) {
    const int tid = threadIdx.x;
    const int r0 = blockIdx.x * 32;
    const int c0 = blockIdx.y * 128;

    __shared__ __align__(16) f16x2 wih_s[I_DIM / 2][128];
    __shared__ __align__(16) f16x2 x_s[32][I_DIM / 2];

#pragma unroll
    for (int i = 0; i < 32; ++i) {
        int idx = i * 256 + tid;
        int kp = idx >> 7;
        int cl = idx & 127;
        float w0 = Wih[(size_t)(2 * kp + 0) * H_DIM + c0 + cl];
        float w1 = Wih[(size_t)(2 * kp + 1) * H_DIM + c0 + cl];
        f16x2 w; w.x = (f16)w0; w.y = (f16)w1;
        wih_s[kp][cl] = w;
    }
    const float4* xs = (const float4*)(x + (size_t)r0 * I_DIM);
    f16x4* xd = (f16x4*)x_s;
#pragma unroll
    for (int i = 0; i < 4; ++i) {
        int idx = i * 256 + tid;
        float4 v = xs[idx];
        f16x4 h; h.x = (f16)v.x; h.y = (f16)v.y; h.z = (f16)v.z; h.w = (f16)v.w;
        xd[idx] = h;
    }
    __syncthreads();

    const int cl = tid & 127;
    const int rh = tid >> 7;
    float acc[16];
#pragma unroll
    for (int r = 0; r < 16; ++r) acc[r] = 0.f;

#pragma unroll
    for (int kc = 0; kc < 2; ++kc) {
        f16x2 wv[32];
#pragma unroll
        for (int i = 0; i < 32; ++i) wv[i] = wih_s[kc * 32 + i][cl];
#pragma unroll
        for (int r = 0; r < 16; ++r) {
            const int row = rh * 16 + r;
#pragma unroll
            for (int m = 0; m < 8; ++m) {
                f16x8 h8v = *(const f16x8*)(&x_s[row][kc * 32 + 4 * m]);
                const f16x2* hp = (const f16x2*)&h8v;
                acc[r] = fdot2f(wv[4 * m + 0], hp[0], acc[r]);
                acc[r] = fdot2f(wv[4 * m + 1], hp[1], acc[r]);
                acc[r] = fdot2f(wv[4 * m + 2], hp[2], acc[r]);
                acc[r] = fdot2f(wv[4 * m + 3], hp[3], acc[r]);
            }
        }
    }
#pragma unroll
    for (int r = 0; r < 16; ++r) {
        int row = r0 + rh * 16 + r;
        u[(size_t)row * H_DIM + c0 + cl] = (f16)acc[r];
    }
}

// ---------------------------------------------------------------------------
// Phase 2: scan via v_dot4_i32_i8 with W fully register-resident.
//
// Why leave MFMA: replicated-A wastes 15/16 of the matrix pipe; any tiling
// of the 512x512 matvec at 16x16x64 needs 256 mfma/CU/step = 1306cy floor
// (R3 measured 1840). v_dot4_i32_i8 does 4 MAC/lane -> 512 MAC/cy/CU ->
// 262144 MAC/step = 512cy issue floor, 2.5x below the MFMA floor. i8 W is
// 256 KB = exactly 128 VGPRs/thread at 512 threads: fully register-resident
// (R0's f16 VALU version died on the 512 KB W not fitting).
//
// Thread (kg=tid&3, cq=tid>>2): K-slice [kg*128,kg*128+128) of columns
// c_i = cq + 128*i (i=0..3). Per step: 8 broadcast ds_read_b128 of the
// h-slice, 128 sdot4 (4 accs x 32), quad butterfly (DPP quad_perm xor1 +
// xor2 — every lane ends with all 4 complete column sums), lane keeps
// column j=(kg+(cq&3))&3 (rotation -> the 1-byte h writes hit distinct
// words: conflict-free), 1 tanh, 1 coalesced-window global store.
//
// h LDS layout: 4 K-slices at stride 144 B (128 data + 16 pad) so the 4
// kg broadcast addresses land on distinct banks. Double-buffered.
//
// R4 FAILURE ROOT-CAUSE: zero-init only covered bytes 0..511 of the 576-byte
// padded h buffer; slice 3's data (bytes 432..559) left k=464..511 of h(0)
// as garbage -> absmax 0.0737. Fixed: explicit tail zeroing below.
//
// Quantization identical to R3 (passed, absmax 0.0078): per-column scale
// 127/max|W[:,c]|, exact i32 accumulate, h operand = rint(127h), h state f32.
// ---------------------------------------------------------------------------
#define SLICE_STRIDE 144   // 128 B data + 16 B pad per K-slice

__global__ __launch_bounds__(512, 2)
void rnn_scan_kernel(const float* __restrict__ Wrec, f16* __restrict__ uhs) {
    const int tid = threadIdx.x;          // 0..511
    const int b = blockIdx.x;
    const int kg = tid & 3;               // K-slice
    const int cq = tid >> 2;              // 0..127 column base

    __shared__ __align__(16) signed char h8[2][4 * SLICE_STRIDE];
    __shared__ float colmax[512];

    // ---- pass 1: per-column max, coalesced (thread tid scans column tid) ----
    {
        const float* wp = Wrec + tid;
        float m0 = 0.f, m1 = 0.f, m2 = 0.f, m3 = 0.f;
        for (int k = 0; k < 512; k += 4) {
            m0 = fmaxf(m0, __builtin_fabsf(wp[(size_t)(k + 0) * H_DIM]));
            m1 = fmaxf(m1, __builtin_fabsf(wp[(size_t)(k + 1) * H_DIM]));
            m2 = fmaxf(m2, __builtin_fabsf(wp[(size_t)(k + 2) * H_DIM]));
            m3 = fmaxf(m3, __builtin_fabsf(wp[(size_t)(k + 3) * H_DIM]));
        }
        float m = fmaxf(fmaxf(m0, m1), fmaxf(m2, m3));
        colmax[tid] = fmaxf(m, 1e-20f);
    }
    // zero h buffer 0 — ALL 576 bytes (R4 bug: bytes 512..575, which include
    // slice 3's data for k=464..511, were left uninitialized).
    h8[0][tid] = 0;
    if (tid < 4 * SLICE_STRIDE - 512) h8[0][512 + tid] = 0;
    __syncthreads();

    // ---- pass 2: quantize + pack W ----
    // w[q][i]: dword q=0..31 packs k = kg*128 + 4q .. +3 (byte e -> k+e) for
    // column c_i = cq + 128*i.
    int wq[32][4];   // 128 VGPRs
#pragma unroll
    for (int i = 0; i < 4; ++i) {
        const int col = cq + 128 * i;
        const float* wp = Wrec + col;
        const float sc = 127.f / colmax[col];
#pragma unroll
        for (int q = 0; q < 32; ++q) {
            int wd = 0;
#pragma unroll
            for (int e = 0; e < 4; ++e) {
                float v = wp[(size_t)(kg * 128 + 4 * q + e) * H_DIM] * sc;
                v = fminf(fmaxf(v, -127.f), 127.f);
                wd |= (((int)rintf(v)) & 255) << (8 * e);
            }
            wq[q][i] = wd;
        }
    }

    // kept column after butterfly: j chosen so quad writes hit distinct words
    const int jk = (kg + (cq & 3)) & 3;
    const int c_own = cq + 128 * jk;
    f16* io = uhs + (size_t)b * S_LEN * H_DIM + c_own;
    const float inv = colmax[c_own] * (1.f / 16129.f);   // colmax/127^2

    float hp = 0.f;
    float uc = (float)io[0];
    f16 ua = (f16)0.f;
    if (S_LEN > 1) ua = io[H_DIM];

    __syncthreads();

    for (int t = 0; t < S_LEN; ++t) {
        // prefetch u(t+2)
        f16 ub = (f16)0.f;
        if (t + 2 < S_LEN) ub = io[(size_t)(t + 2) * H_DIM];

        const signed char* hb = h8[t & 1] + kg * SLICE_STRIDE;
        i32x4 av[8];
#pragma unroll
        for (int m = 0; m < 8; ++m)
            av[m] = *(const i32x4*)(hb + 16 * m);   // broadcast per kg, padded

        int ac0 = 0, ac1 = 0, ac2 = 0, ac3 = 0;
#pragma unroll
        for (int m = 0; m < 8; ++m) {
#pragma unroll
            for (int d = 0; d < 4; ++d) {
                const int q = 4 * m + d;
                const int hv = av[m][d];
                ac0 = sdot4(hv, wq[q][0], ac0);
                ac1 = sdot4(hv, wq[q][1], ac1);
                ac2 = sdot4(hv, wq[q][2], ac2);
                ac3 = sdot4(hv, wq[q][3], ac3);
            }
        }

        // quad butterfly: sum the 4 kg partials (all lanes get full sums)
        ac0 += dpp_qi<0xB1>(ac0);  ac1 += dpp_qi<0xB1>(ac1);
        ac2 += dpp_qi<0xB1>(ac2);  ac3 += dpp_qi<0xB1>(ac3);
        ac0 += dpp_qi<0x4E>(ac0);  ac1 += dpp_qi<0x4E>(ac1);
        ac2 += dpp_qi<0x4E>(ac2);  ac3 += dpp_qi<0x4E>(ac3);

        int zi = jk == 0 ? ac0 : jk == 1 ? ac1 : jk == 2 ? ac2 : ac3;
        float z = (float)zi * inv + uc;

        // tanh(z) = 1 - 2/(exp(2z)+1)
        float e2 = __expf(2.f * z);
        float r = 1.f - 2.f * __builtin_amdgcn_rcpf(e2 + 1.f);
        hp = 0.8f * hp + 0.2f * r;

        // next h: slice jk, offset cq (distinct words across the quad)
        h8[(t + 1) & 1][jk * SLICE_STRIDE + cq] =
            (signed char)(int)rintf(hp * 127.f);
        io[(size_t)t * H_DIM] = (f16)hp;      // hs (f16, phase-3 input)

        uc = (float)ua;
        ua = ub;
        __syncthreads();
    }
}

// ---------------------------------------------------------------------------
// Phase 3: out[row][o] = sum_k hs[row][k] * Who[k][o], K=512, O=64, fp32 out.
// (unchanged)
// ---------------------------------------------------------------------------
__global__ __launch_bounds__(256)
void out_gemm_kernel(const f16* __restrict__ hs, const float* __restrict__ Who,
                     float* __restrict__ out) {
    const int tid = threadIdx.x;
    const int r0 = blockIdx.x * 32;

    __shared__ __align__(16) f16x2 who_s[128][O_DIM];
    __shared__ __align__(16) f16x2 hs_s[32][128];

    const int o = tid & 63;
    const int rg = tid >> 6;

    float acc[8];
#pragma unroll
    for (int r = 0; r < 8; ++r) acc[r] = 0.f;

    for (int kc = 0; kc < 2; ++kc) {
        if (kc) __syncthreads();
#pragma unroll
        for (int i = 0; i < 32; ++i) {
            int idx = i * 256 + tid;
            int kp = idx >> 6;
            int oc = idx & 63;
            float w0 = Who[(size_t)(kc * 256 + 2 * kp + 0) * O_DIM + oc];
            float w1 = Who[(size_t)(kc * 256 + 2 * kp + 1) * O_DIM + oc];
            f16x2 wv2; wv2.x = (f16)w0; wv2.y = (f16)w1;
            who_s[kp][oc] = wv2;
        }
        f16x8* hd = (f16x8*)hs_s;
#pragma unroll
        for (int i = 0; i < 4; ++i) {
            int idx = i * 256 + tid;
            int r = idx >> 5;
            int m = idx & 31;
            f16x8 v = *(const f16x8*)(hs + (size_t)(r0 + r) * H_DIM + kc * 256 + m * 8);
            hd[idx] = v;
        }
        __syncthreads();

#pragma unroll
        for (int sc = 0; sc < 4; ++sc) {
            f16x2 wv[32];
#pragma unroll
            for (int i = 0; i < 32; ++i) wv[i] = who_s[sc * 32 + i][o];
#pragma unroll
            for (int r = 0; r < 8; ++r) {
                const int row = rg * 8 + r;
#pragma unroll
                for (int m = 0; m < 8; ++m) {
                    f16x8 h8v = *(const f16x8*)(&hs_s[row][sc * 32 + 4 * m]);
                    const f16x2* hp = (const f16x2*)&h8v;
                    acc[r] = fdot2f(wv[4 * m + 0], hp[0], acc[r]);
                    acc[r] = fdot2f(wv[4 * m + 1], hp[1], acc[r]);
                    acc[r] = fdot2f(wv[4 * m + 2], hp[2], acc[r]);
                    acc[r] = fdot2f(wv[4 * m + 3], hp[3], acc[r]);
                }
            }
        }
    }
#pragma unroll
    for (int r = 0; r < 8; ++r) {
        int row = r0 + rg * 8 + r;
        out[(size_t)row * O_DIM + o] = acc[r];
    }
}

extern "C" void kernel_launch(void* const* d_in, const int* in_sizes, int n_in,
                              void* d_out, int out_size, void* d_ws, size_t ws_size,
                              hipStream_t stream) {
    const float* x    = (const float*)d_in[0];   // [64][2048][128]
    const float* Wih  = (const float*)d_in[1];   // [128][512]
    const float* Wrec = (const float*)d_in[2];   // [512][512]
    const float* Who  = (const float*)d_in[3];   // [512][64]
    float* out = (float*)d_out;                  // [64][2048][64]
    f16* uhs = (f16*)d_ws;                       // 128 MB: u, then hs in-place

    const int R = BATCH * S_LEN;

    u_gemm_kernel<<<dim3(R / 32, H_DIM / 128), 256, 0, stream>>>(x, Wih, uhs);
    rnn_scan_kernel<<<dim3(BATCH), 512, 0, stream>>>(Wrec, uhs);
    out_gemm_kernel<<<dim3(R / 32), 256, 0, stream>>>(uhs, Who, out);
}